// Round 1
// baseline (284.336 us; speedup 1.0000x reference)
//
#include <hip/hip_runtime.h>
#include <cfloat>
#include <cmath>

// Problem constants (from reference):
//   inputs  [16,8,512,64] fp32  -> N=65536 rows, D=64
//   weight  [512,64] fp32       -> K=512 codes
// Outputs concatenated in d_out (fp32):
//   [0]                loss (scalar)
//   [1 .. 4194304]     quantized_st  (N*D)
//   [4194305]          perplexity (scalar)
//   [4194306 .. end]   encodings (N*K one-hot)

#define NROWS   65536
#define DDIM    64
#define KCODES  512
#define OFF_LOSS  0
#define OFF_QUANT 1
#define OFF_PERP  4194305
#define OFF_ENC   4194306
#define VQ_EPS  1.1920929e-7f

// ws layout (u32 units): [0] = sse (float, atomic), [16..527] = counts (u32)

__global__ void vq_init(unsigned* __restrict__ ws) {
    int t = threadIdx.x;
    for (int i = t; i < 544; i += 256) ws[i] = 0u;
}

__global__ void __launch_bounds__(256, 1)
vq_main(const float* __restrict__ x, const float* __restrict__ w,
        float* __restrict__ out, float* __restrict__ ws)
{
    extern __shared__ float smem[];
    float* wt    = smem;                    // [64][512] transposed weights, 128 KB
    float* xlds  = smem + 64 * 512;         // [4][8][64] per-wave row tiles, 8 KB
    float* xnorm = xlds + 4 * 8 * 64;       // [4][8]
    unsigned* hist = (unsigned*)(xnorm + 32); // [512]

    const int t    = threadIdx.x;
    const int lane = t & 63;
    const int wid  = t >> 6;

    for (int i = t; i < 512; i += 256) hist[i] = 0u;

    // ---- stage W transposed into LDS (coalesced global read, scalar LDS writes)
    for (int i = 0; i < 32; ++i) {
        int e  = (t << 2) + (i << 10);      // element index into w (row-major [512][64])
        float4 v = *(const float4*)(w + e);
        int k  = e >> 6;
        int d0 = e & 63;
        wt[((d0 + 0) << 9) + k] = v.x;
        wt[((d0 + 1) << 9) + k] = v.y;
        wt[((d0 + 2) << 9) + k] = v.z;
        wt[((d0 + 3) << 9) + k] = v.w;
    }
    __syncthreads();

    // ---- per-lane ||w_k||^2 for codes k = j*64 + lane
    float wn[8];
#pragma unroll
    for (int j = 0; j < 8; ++j) wn[j] = 0.f;
    for (int d = 0; d < 64; ++d) {
#pragma unroll
        for (int j = 0; j < 8; ++j) {
            float v = wt[(d << 9) + (j << 6) + lane];
            wn[j] = fmaf(v, v, wn[j]);
        }
    }

    float sse = 0.f;
    const int blockRow = blockIdx.x << 8;          // 256 rows per block
    const int waveRow0 = blockRow + (wid << 6);    // 64 rows per wave
    float* myx = xlds + (wid << 9);                // [8][64]

    for (int iter = 0; iter < 8; ++iter) {
        const int row0 = waveRow0 + (iter << 3);

        // ---- stage 8 rows of x into LDS (wave-private, no barrier needed)
        {
            const float* src = x + ((size_t)row0 << 6) + (lane << 3);
            float4 a = *(const float4*)src;
            float4 b = *(const float4*)(src + 4);
            int r  = lane >> 3;
            int d0 = (lane & 7) << 3;
            *(float4*)(myx + (r << 6) + d0)     = a;
            *(float4*)(myx + (r << 6) + d0 + 4) = b;
            float pn = a.x*a.x + a.y*a.y + a.z*a.z + a.w*a.w
                     + b.x*b.x + b.y*b.y + b.z*b.z + b.w*b.w;
            pn += __shfl_xor(pn, 1);
            pn += __shfl_xor(pn, 2);
            pn += __shfl_xor(pn, 4);
            if ((lane & 7) == 0) xnorm[(wid << 3) + r] = pn;
        }

        // ---- dot products: s[r][j] = x_row(r) . w_code(j*64+lane)
        float s[8][8];
#pragma unroll
        for (int r = 0; r < 8; ++r)
#pragma unroll
            for (int j = 0; j < 8; ++j) s[r][j] = 0.f;

#pragma unroll 4
        for (int d = 0; d < 64; ++d) {
            float wvv[8];
#pragma unroll
            for (int j = 0; j < 8; ++j) wvv[j] = wt[(d << 9) + (j << 6) + lane];
#pragma unroll
            for (int r = 0; r < 8; ++r) {
                float xv = myx[(r << 6) + d];
#pragma unroll
                for (int j = 0; j < 8; ++j) s[r][j] = fmaf(xv, wvv[j], s[r][j]);
            }
        }

        // ---- argmin over 512 codes per row (mimic reference rounding order)
        int bk_arr[8];
#pragma unroll
        for (int r = 0; r < 8; ++r) {
            float xn = xnorm[(wid << 3) + r];
            float bv = FLT_MAX;
            int   bk = 0;
#pragma unroll
            for (int j = 0; j < 8; ++j) {
                float dv = (xn + wn[j]) - 2.0f * s[r][j];
                if (dv < bv) { bv = dv; bk = (j << 6) + lane; }
            }
#pragma unroll
            for (int off = 1; off < 64; off <<= 1) {
                float ov = __shfl_xor(bv, off);
                int   ok = __shfl_xor(bk, off);
                if (ov < bv || (ov == bv && ok < bk)) { bv = ov; bk = ok; }
            }
            bk_arr[r] = bk;
        }

        // ---- gather codebook rows (coalesced 256B reads, L1/L2-resident)
        float wq[8];
#pragma unroll
        for (int r = 0; r < 8; ++r) wq[r] = w[((size_t)bk_arr[r] << 6) + lane];

        // ---- writes: quantized_st, loss partial, encodings, histogram
#pragma unroll
        for (int r = 0; r < 8; ++r) {
            const int row = row0 + r;
            float xval = myx[(r << 6) + lane];
            float q    = wq[r];
            out[OFF_QUANT + ((size_t)row << 6) + lane] = xval + (q - xval);
            float df = q - xval;
            sse = fmaf(df, df, sse);

            float2* ebase = (float2*)(out + OFF_ENC + ((size_t)row << 9) + (lane << 3));
            int kk = bk_arr[r];
#pragma unroll
            for (int m = 0; m < 4; ++m) {
                float2 f = make_float2(0.f, 0.f);
                if ((kk >> 1) == ((lane << 2) + m)) {
                    if (kk & 1) f.y = 1.f; else f.x = 1.f;
                }
                ebase[m] = f;
            }
            if (lane == 0) atomicAdd(&hist[kk], 1u);
        }
    }

    // ---- block-level loss partial
#pragma unroll
    for (int off = 1; off < 64; off <<= 1) sse += __shfl_xor(sse, off);
    if (lane == 0) atomicAdd((float*)ws, sse);

    __syncthreads();
    for (int i = t; i < 512; i += 256) {
        unsigned c = hist[i];
        if (c) atomicAdd(((unsigned*)ws) + 16 + i, c);
    }
}

__global__ void vq_fin(const unsigned* __restrict__ ws, float* __restrict__ out)
{
    __shared__ float red[8];
    int t = threadIdx.x;   // 512 threads
    unsigned c = ws[16 + t];
    float p = (float)c * (1.0f / 65536.0f);
    float v = p * logf(p + VQ_EPS);
#pragma unroll
    for (int off = 1; off < 64; off <<= 1) v += __shfl_xor(v, off);
    if ((t & 63) == 0) red[t >> 6] = v;
    __syncthreads();
    if (t == 0) {
        float s2 = 0.f;
#pragma unroll
        for (int i = 0; i < 8; ++i) s2 += red[i];
        out[OFF_PERP] = expf(-s2);
        float sse = ((const float*)ws)[0];
        float m = sse * (1.0f / 4194304.0f);   // mean((q-x)^2)
        out[OFF_LOSS] = m + 0.25f * m;         // q_latent + commitment*e_latent
    }
}

extern "C" void kernel_launch(void* const* d_in, const int* in_sizes, int n_in,
                              void* d_out, int out_size, void* d_ws, size_t ws_size,
                              hipStream_t stream) {
    const float* x = (const float*)d_in[0];
    const float* w = (const float*)d_in[1];
    float* out = (float*)d_out;
    unsigned* ws = (unsigned*)d_ws;

    // dynamic LDS: wt(128K) + xlds(8K) + xnorm(128B) + hist(2K)
    const size_t smem = (size_t)(64 * 512 + 4 * 8 * 64 + 32 + 512) * 4;
    (void)hipFuncSetAttribute((const void*)vq_main,
                              hipFuncAttributeMaxDynamicSharedMemorySize, (int)smem);

    hipLaunchKernelGGL(vq_init, dim3(1), dim3(256), 0, stream, ws);
    hipLaunchKernelGGL(vq_main, dim3(256), dim3(256), smem, stream, x, w, out, (float*)ws);
    hipLaunchKernelGGL(vq_fin,  dim3(1), dim3(512), 0, stream, ws, out);
}

// Round 2
// 264.705 us; speedup vs baseline: 1.0742x; 1.0742x over previous
//
#include <hip/hip_runtime.h>
#include <cfloat>
#include <cmath>

// Problem: VectorQuantizer. inputs [16,8,512,64] fp32 (N=65536 rows, D=64),
// weight [512,64] fp32 (K=512). Outputs concat fp32:
//   [0] loss | [1..4194304] quantized_st | [4194305] perplexity | [4194306..] encodings (N*K)

#define OFF_LOSS  0
#define OFF_QUANT 1
#define OFF_PERP  4194305
#define OFF_ENC   4194306
#define VQ_EPS  1.1920929e-7f

// ws layout (u32): [0] sse(float), [16..527] counts

// swizzled transposed-W LDS index: kills 16-way bank conflicts on staging
// writes (fixed k, d strided 4 -> (d>>2)&15 distinct) while keeping reads
// (fixed d, consecutive k) conflict-free (XOR const < 64 permutes in-row).
#define WTI(d,k) (((d)<<9) + ((k) ^ ((((d)>>2))&15)))

__global__ void vq_init(unsigned* __restrict__ ws) {
    int t = threadIdx.x;
    if (t < 544) ws[t] = 0u;
}

__global__ void __launch_bounds__(1024)
vq_main(const float* __restrict__ x, const float* __restrict__ w,
        float* __restrict__ out, float* __restrict__ ws)
{
    extern __shared__ float smem[];
    float* wt   = smem;            // swizzled [64][512] transposed W, 128 KB
    float* xlds = smem + 64 * 512; // [16 waves][8 rows][64], 32 KB

    const int t    = threadIdx.x;
    const int lane = t & 63;
    const int wid  = t >> 6;

    // ---- stage W transposed+swizzled (coalesced float4 global reads)
#pragma unroll
    for (int i = 0; i < 8; ++i) {
        int e  = (t << 2) + (i << 12);       // element in w [512][64]
        float4 v = *(const float4*)(w + e);
        int k  = e >> 6;
        int d0 = e & 63;
        wt[WTI(d0 + 0, k)] = v.x;
        wt[WTI(d0 + 1, k)] = v.y;
        wt[WTI(d0 + 2, k)] = v.z;
        wt[WTI(d0 + 3, k)] = v.w;
    }
    __syncthreads();

    // ---- per-lane ||w_k||^2, codes k = j*64+lane (sequential d: keep exact
    //      rounding order that matched the reference bit-for-bit)
    float wn[8];
#pragma unroll
    for (int j = 0; j < 8; ++j) wn[j] = 0.f;
    for (int d = 0; d < 64; ++d) {
#pragma unroll
        for (int j = 0; j < 8; ++j) {
            float v = wt[WTI(d, (j << 6) + lane)];
            wn[j] = fmaf(v, v, wn[j]);
        }
    }

    float sse = 0.f;
    const int waveRow0 = (blockIdx.x << 8) + (wid << 4);  // 256 rows/block, 16/wave
    float* myx = xlds + (wid << 9);                       // [8][64]

    for (int iter = 0; iter < 2; ++iter) {
        const int row0 = waveRow0 + (iter << 3);

        // ---- stage 8 rows of x (wave-private; DS ops in-order within wave)
        float xn_bc;
        {
            const float* src = x + ((size_t)row0 << 6) + (lane << 3);
            float4 a = *(const float4*)src;
            float4 b = *(const float4*)(src + 4);
            int r  = lane >> 3;
            int d0 = (lane & 7) << 3;
            *(float4*)(myx + (r << 6) + d0)     = a;
            *(float4*)(myx + (r << 6) + d0 + 4) = b;
            float pn = a.x*a.x + a.y*a.y + a.z*a.z + a.w*a.w
                     + b.x*b.x + b.y*b.y + b.z*b.z + b.w*b.w;
            pn += __shfl_xor(pn, 1);
            pn += __shfl_xor(pn, 2);
            pn += __shfl_xor(pn, 4);
            xn_bc = pn;  // lanes r*8..r*8+7 hold ||x_row(r)||^2
        }

        // ---- s[r][j] = x_row(row0+r) . w_code(j*64+lane)
        float s[8][8];
#pragma unroll
        for (int r = 0; r < 8; ++r)
#pragma unroll
            for (int j = 0; j < 8; ++j) s[r][j] = 0.f;

#pragma unroll 4
        for (int d = 0; d < 64; ++d) {
            float wvv[8];
#pragma unroll
            for (int j = 0; j < 8; ++j) wvv[j] = wt[WTI(d, (j << 6) + lane)];
#pragma unroll
            for (int r = 0; r < 8; ++r) {
                float xv = myx[(r << 6) + d];
#pragma unroll
                for (int j = 0; j < 8; ++j) s[r][j] = fmaf(xv, wvv[j], s[r][j]);
            }
        }

        // ---- argmin per row (identical formula + tie-break as before)
        int bk_arr[8];
#pragma unroll
        for (int r = 0; r < 8; ++r) {
            float xn = __shfl(xn_bc, r << 3);
            float bv = FLT_MAX;
            int   bk = 0;
#pragma unroll
            for (int j = 0; j < 8; ++j) {
                float dv = (xn + wn[j]) - 2.0f * s[r][j];
                if (dv < bv) { bv = dv; bk = (j << 6) + lane; }
            }
#pragma unroll
            for (int off = 1; off < 64; off <<= 1) {
                float ov = __shfl_xor(bv, off);
                int   ok = __shfl_xor(bk, off);
                if (ov < bv || (ov == bv && ok < bk)) { bv = ov; bk = ok; }
            }
            bk_arr[r] = bk;
        }

        // ---- gather codebook rows (L2-resident)
        float wq[8];
#pragma unroll
        for (int r = 0; r < 8; ++r) wq[r] = w[((size_t)bk_arr[r] << 6) + lane];

        // ---- outputs: quantized_st, sse, one-hot (2x float4), histogram
#pragma unroll
        for (int r = 0; r < 8; ++r) {
            const int row = row0 + r;
            float xval = myx[(r << 6) + lane];
            float q    = wq[r];
            out[OFF_QUANT + ((size_t)row << 6) + lane] = xval + (q - xval);
            float df = q - xval;
            sse = fmaf(df, df, sse);

            int kk = bk_arr[r];
            int b  = lane << 3;
            float4 z0, z1;
            z0.x = (kk == b + 0) ? 1.f : 0.f;
            z0.y = (kk == b + 1) ? 1.f : 0.f;
            z0.z = (kk == b + 2) ? 1.f : 0.f;
            z0.w = (kk == b + 3) ? 1.f : 0.f;
            z1.x = (kk == b + 4) ? 1.f : 0.f;
            z1.y = (kk == b + 5) ? 1.f : 0.f;
            z1.z = (kk == b + 6) ? 1.f : 0.f;
            z1.w = (kk == b + 7) ? 1.f : 0.f;
            float4* ebase = (float4*)(out + OFF_ENC + ((size_t)row << 9) + (lane << 3));
            ebase[0] = z0;
            ebase[1] = z1;
            if (lane == r) atomicAdd(((unsigned*)ws) + 16 + kk, 1u);
        }
    }

    // ---- loss partial
#pragma unroll
    for (int off = 1; off < 64; off <<= 1) sse += __shfl_xor(sse, off);
    if (lane == 0) atomicAdd((float*)ws, sse);
}

__global__ void vq_fin(const unsigned* __restrict__ ws, float* __restrict__ out)
{
    __shared__ float red[8];
    int t = threadIdx.x;   // 512 threads
    unsigned c = ws[16 + t];
    float p = (float)c * (1.0f / 65536.0f);
    float v = p * logf(p + VQ_EPS);
#pragma unroll
    for (int off = 1; off < 64; off <<= 1) v += __shfl_xor(v, off);
    if ((t & 63) == 0) red[t >> 6] = v;
    __syncthreads();
    if (t == 0) {
        float s2 = 0.f;
#pragma unroll
        for (int i = 0; i < 8; ++i) s2 += red[i];
        out[OFF_PERP] = expf(-s2);
        float sse = ((const float*)ws)[0];
        float m = sse * (1.0f / 4194304.0f);
        out[OFF_LOSS] = m + 0.25f * m;
    }
}

extern "C" void kernel_launch(void* const* d_in, const int* in_sizes, int n_in,
                              void* d_out, int out_size, void* d_ws, size_t ws_size,
                              hipStream_t stream) {
    const float* x = (const float*)d_in[0];
    const float* w = (const float*)d_in[1];
    float* out = (float*)d_out;
    unsigned* ws = (unsigned*)d_ws;

    const size_t smem = (size_t)(64 * 512 + 16 * 8 * 64) * 4;  // 160 KiB exactly
    (void)hipFuncSetAttribute((const void*)vq_main,
                              hipFuncAttributeMaxDynamicSharedMemorySize, (int)smem);

    hipLaunchKernelGGL(vq_init, dim3(1), dim3(1024), 0, stream, ws);
    hipLaunchKernelGGL(vq_main, dim3(256), dim3(1024), smem, stream, x, w, out, (float*)ws);
    hipLaunchKernelGGL(vq_fin,  dim3(1), dim3(512), 0, stream, ws, out);
}

// Round 4
// 252.840 us; speedup vs baseline: 1.1246x; 1.0469x over previous
//
#include <hip/hip_runtime.h>
#include <cfloat>
#include <cmath>

// Problem: VectorQuantizer. inputs [16,8,512,64] fp32 (N=65536 rows, D=64),
// weight [512,64] fp32 (K=512). Outputs concat fp32:
//   [0] loss | [1..4194304] quantized_st | [4194305] perplexity | [4194306..] encodings (N*K)

#define OFF_LOSS  0
#define OFF_QUANT 1
#define OFF_PERP  4194305
#define OFF_ENC   4194306
#define VQ_EPS  1.1920929e-7f

// ws layout (u32): [0] sse(float), [16..527] counts

// swizzled transposed-W LDS index. XOR constant only touches lane bits
// (c<16, k=j*64+lane) so reads become base(d, lane^c) + imm offset j*256B.
#define WTI(d,k) (((d)<<9) + ((k) ^ ((((d)>>2))&15)))

__global__ void vq_init(unsigned* __restrict__ ws) {
    int t = threadIdx.x;
    if (t < 544) ws[t] = 0u;
}

__global__ void __launch_bounds__(1024, 4)   // 4 waves/EU: LDS caps at 1 block/CU anyway -> VGPR budget 128
vq_main(const float* __restrict__ x, const float* __restrict__ w,
        float* __restrict__ out, float* __restrict__ ws)
{
    extern __shared__ float smem[];
    float* wt   = smem;            // swizzled [64][512] transposed W, 128 KB
    float* xlds = smem + 64 * 512; // [16 waves][8 rows][64], 32 KB

    const int t    = threadIdx.x;
    const int lane = t & 63;
    const int wid  = t >> 6;

    // ---- stage W transposed+swizzled (coalesced float4 global reads)
#pragma unroll
    for (int i = 0; i < 8; ++i) {
        int e  = (t << 2) + (i << 12);       // element in w [512][64]
        float4 v = *(const float4*)(w + e);
        int k  = e >> 6;
        int d0 = e & 63;
        wt[WTI(d0 + 0, k)] = v.x;
        wt[WTI(d0 + 1, k)] = v.y;
        wt[WTI(d0 + 2, k)] = v.z;
        wt[WTI(d0 + 3, k)] = v.w;
    }
    __syncthreads();

    // ---- per-lane ||w_k||^2, codes k = j*64+lane (sequential d -> exact
    //      rounding order that matched the reference bit-for-bit)
    float wn[8];
#pragma unroll
    for (int j = 0; j < 8; ++j) wn[j] = 0.f;
    for (int d = 0; d < 64; ++d) {
        const float* pw = wt + (d << 9) + (lane ^ ((d >> 2) & 15));
#pragma unroll
        for (int j = 0; j < 8; ++j) {
            float v = pw[j << 6];
            wn[j] = fmaf(v, v, wn[j]);
        }
    }

    float sse = 0.f;
    const int waveRow0 = (blockIdx.x << 8) + (wid << 4);  // 256 rows/block, 16/wave
    float* myx = xlds + (wid << 9);                       // [8][64]

    for (int iter = 0; iter < 2; ++iter) {
        const int row0 = waveRow0 + (iter << 3);

        // ---- stage 8 rows of x (wave-private; DS ops in-order within wave)
        float xn_bc;
        {
            const float* src = x + ((size_t)row0 << 6) + (lane << 3);
            float4 a = *(const float4*)src;
            float4 b = *(const float4*)(src + 4);
            int r  = lane >> 3;
            int d0 = (lane & 7) << 3;
            *(float4*)(myx + (r << 6) + d0)     = a;
            *(float4*)(myx + (r << 6) + d0 + 4) = b;
            float pn = a.x*a.x + a.y*a.y + a.z*a.z + a.w*a.w
                     + b.x*b.x + b.y*b.y + b.z*b.z + b.w*b.w;
            pn += __shfl_xor(pn, 1);
            pn += __shfl_xor(pn, 2);
            pn += __shfl_xor(pn, 4);
            xn_bc = pn;  // lanes r*8..r*8+7 hold ||x_row(r)||^2
        }

        // ---- s[r][j] = x_row(row0+r) . w_code(j*64+lane)
        float s[8][8];
#pragma unroll
        for (int r = 0; r < 8; ++r)
#pragma unroll
            for (int j = 0; j < 8; ++j) s[r][j] = 0.f;

#pragma unroll 4
        for (int d = 0; d < 64; ++d) {
            const float* pw = wt + (d << 9) + (lane ^ ((d >> 2) & 15));
            const float* px = myx + d;
            float wvv[8];
#pragma unroll
            for (int j = 0; j < 8; ++j) wvv[j] = pw[j << 6];   // ds_read base+imm
#pragma unroll
            for (int r = 0; r < 8; ++r) {
                float xv = px[r << 6];                         // broadcast read
#pragma unroll
                for (int j = 0; j < 8; ++j) s[r][j] = fmaf(xv, wvv[j], s[r][j]);
            }
        }

        // ---- argmin per row (identical formula + tie-break)
        int bk_arr[8];
#pragma unroll
        for (int r = 0; r < 8; ++r) {
            float xn = __shfl(xn_bc, r << 3);
            float bv = FLT_MAX;
            int   bk = 0;
#pragma unroll
            for (int j = 0; j < 8; ++j) {
                float dv = (xn + wn[j]) - 2.0f * s[r][j];
                if (dv < bv) { bv = dv; bk = (j << 6) + lane; }
            }
#pragma unroll
            for (int off = 1; off < 64; off <<= 1) {
                float ov = __shfl_xor(bv, off);
                int   ok = __shfl_xor(bk, off);
                if (ov < bv || (ov == bv && ok < bk)) { bv = ov; bk = ok; }
            }
            bk_arr[r] = bk;
        }

        // ---- gather codebook rows (L2-resident)
        float wq[8];
#pragma unroll
        for (int r = 0; r < 8; ++r) wq[r] = w[((size_t)bk_arr[r] << 6) + lane];

        // ---- outputs: quantized_st, sse, one-hot (2x float4), histogram
#pragma unroll
        for (int r = 0; r < 8; ++r) {
            const int row = row0 + r;
            float xval = myx[(r << 6) + lane];
            float q    = wq[r];
            out[OFF_QUANT + ((size_t)row << 6) + lane] = xval + (q - xval);
            float df = q - xval;
            sse = fmaf(df, df, sse);

            int kk = bk_arr[r];
            int b  = lane << 3;
            float4 z0, z1;
            z0.x = (kk == b + 0) ? 1.f : 0.f;
            z0.y = (kk == b + 1) ? 1.f : 0.f;
            z0.z = (kk == b + 2) ? 1.f : 0.f;
            z0.w = (kk == b + 3) ? 1.f : 0.f;
            z1.x = (kk == b + 4) ? 1.f : 0.f;
            z1.y = (kk == b + 5) ? 1.f : 0.f;
            z1.z = (kk == b + 6) ? 1.f : 0.f;
            z1.w = (kk == b + 7) ? 1.f : 0.f;
            float4* ebase = (float4*)(out + OFF_ENC + ((size_t)row << 9) + (lane << 3));
            ebase[0] = z0;
            ebase[1] = z1;
            if (lane == r) atomicAdd(((unsigned*)ws) + 16 + kk, 1u);
        }
    }

    // ---- loss partial
#pragma unroll
    for (int off = 1; off < 64; off <<= 1) sse += __shfl_xor(sse, off);
    if (lane == 0) atomicAdd((float*)ws, sse);
}

__global__ void vq_fin(const unsigned* __restrict__ ws, float* __restrict__ out)
{
    __shared__ float red[8];
    int t = threadIdx.x;   // 512 threads
    unsigned c = ws[16 + t];
    float p = (float)c * (1.0f / 65536.0f);
    float v = p * logf(p + VQ_EPS);
#pragma unroll
    for (int off = 1; off < 64; off <<= 1) v += __shfl_xor(v, off);
    if ((t & 63) == 0) red[t >> 6] = v;
    __syncthreads();
    if (t == 0) {
        float s2 = 0.f;
#pragma unroll
        for (int i = 0; i < 8; ++i) s2 += red[i];
        out[OFF_PERP] = expf(-s2);
        float sse = ((const float*)ws)[0];
        float m = sse * (1.0f / 4194304.0f);
        out[OFF_LOSS] = m + 0.25f * m;
    }
}

extern "C" void kernel_launch(void* const* d_in, const int* in_sizes, int n_in,
                              void* d_out, int out_size, void* d_ws, size_t ws_size,
                              hipStream_t stream) {
    const float* x = (const float*)d_in[0];
    const float* w = (const float*)d_in[1];
    float* out = (float*)d_out;
    unsigned* ws = (unsigned*)d_ws;

    const size_t smem = (size_t)(64 * 512 + 16 * 8 * 64) * 4;  // 160 KiB exactly
    (void)hipFuncSetAttribute((const void*)vq_main,
                              hipFuncAttributeMaxDynamicSharedMemorySize, (int)smem);

    hipLaunchKernelGGL(vq_init, dim3(1), dim3(1024), 0, stream, ws);
    hipLaunchKernelGGL(vq_main, dim3(256), dim3(1024), smem, stream, x, w, out, (float*)ws);
    hipLaunchKernelGGL(vq_fin,  dim3(1), dim3(512), 0, stream, ws, out);
}